// Round 4
// baseline (371.043 us; speedup 1.0000x reference)
//
#include <hip/hip_runtime.h>

#define B_ 16
#define C_ 512
#define S_ 128
#define T_ 2048
#define HALF 18
#define WLEN 37

typedef __bf16 bf16x8 __attribute__((ext_vector_type(8)));
typedef float f32x4 __attribute__((ext_vector_type(4)));
typedef float f32x16 __attribute__((ext_vector_type(16)));
typedef unsigned short ushort_t;

__device__ inline ushort_t f2bf(float x) {
    unsigned u = __float_as_uint(x);
    u += 0x7fffu + ((u >> 16) & 1u);  // RNE; inputs are finite
    return (ushort_t)(u >> 16);
}
__device__ inline float bf2f(ushort_t h) {
    return __uint_as_float(((unsigned)h) << 16);
}
__device__ inline float fast_tanh(float z) {
    float e = __expf(2.f * z);
    return 1.f - __fdividef(2.f, e + 1.f);
}
__device__ __forceinline__ void glds16(const void* g, void* l) {
    __builtin_amdgcn_global_load_lds(
        (const __attribute__((address_space(1))) unsigned*)g,
        (__attribute__((address_space(3))) unsigned*)l, 16, 0, 0);
}

#define MFMA16(a, b, c) __builtin_amdgcn_mfma_f32_16x16x32_bf16((a), (b), (c), 0, 0, 0)
#define MFMA32(a, b, c) __builtin_amdgcn_mfma_f32_32x32x16_bf16((a), (b), (c), 0, 0, 0)

// ---------------- fc weight prep: fp32 -> bf16 ----------------------------------
__global__ void prep_weights(const float* __restrict__ fc1, const float* __restrict__ fc2,
                             ushort_t* __restrict__ Wfc) {
    const int n_fc = 1024 * 128;
    int idx = blockIdx.x * blockDim.x + threadIdx.x;
    if (idx < n_fc) Wfc[idx] = f2bf(fc1[idx]);
    else if (idx < 2 * n_fc) Wfc[idx] = f2bf(fc2[idx - n_fc]);
}

// ---------------- conv weight images: pre-built LDS tiles for global_load_lds ---
// Image layout per conv: [mb(2)][ch(16)] chunks of 53248 B. Each chunk IS the
// padded LDS A-tile [256 rows][13 granules of 16B]: granule g<12 -> tap=g>>2,
// seg=g&3 holds w[o=mb*256+r][i=ch*32+seg*8+e][tap]; g==12 is bank-conflict
// padding (zeros). Row stride 208 B (13 granules, odd -> conflict-free reads).
#define IMGCH 53248    // 52 x 1024 per (mb,ch) chunk
#define A_BYTES 53248  // LDS A buffer (52 granule-KB)
#define B_BYTES 22528  // LDS B buffer (22 granule-KB; 258 rows x 80 B + tail)
__global__ void prep_conv_images(const float* __restrict__ c1, const float* __restrict__ c2,
                                 ushort_t* __restrict__ I1, ushort_t* __restrict__ I2) {
    int idx = blockIdx.x * blockDim.x + threadIdx.x;  // granule id
    const int per_conv = 2 * 16 * 256 * 13;           // 106496 granules
    if (idx >= 2 * per_conv) return;
    int conv = idx >= per_conv;
    int rr = conv ? idx - per_conv : idx;
    const float* src = conv ? c2 : c1;
    ushort_t* dst = conv ? I2 : I1;
    int imgchunk = rr / 3328;  // 256*13
    int rem = rr - imgchunk * 3328;
    int r = rem / 13;
    int g = rem - r * 13;
    int mb = imgchunk >> 4, ch = imgchunk & 15;
    ushort_t vals[8];
    if (g == 12) {
#pragma unroll
        for (int e = 0; e < 8; ++e) vals[e] = 0;
    } else {
        int tap = g >> 2, seg = g & 3;
        int o = mb * 256 + r;
        int chb = ch * 32 + seg * 8;
#pragma unroll
        for (int e = 0; e < 8; ++e)
            vals[e] = f2bf(src[(size_t)(o * 512 + chb + e) * 3 + tap]);
    }
    uint4 pk;
    pk.x = vals[0] | ((unsigned)vals[1] << 16);
    pk.y = vals[2] | ((unsigned)vals[3] << 16);
    pk.z = vals[4] | ((unsigned)vals[5] << 16);
    pk.w = vals[6] | ((unsigned)vals[7] << 16);
    *(uint4*)&dst[(size_t)rr * 8] = pk;
}

// ---------------- zero the halo rows (t=-1, t=T) of both padded buffers --------
__global__ void zero_pads(ushort_t* __restrict__ y1p, ushort_t* __restrict__ y2p) {
    int tid = blockIdx.x * blockDim.x + threadIdx.x;
    if (tid < 4096) {
        ushort_t* base = (tid & 1) ? y2p : y1p;
        int r = tid >> 1;
        int bb = r >> 7;
        int rowsel = (r >> 6) & 1;
        int col = (r & 63) * 8;
        size_t row = (size_t)bb * (T_ + 2) + (rowsel ? (T_ + 1) : 0);
        *(uint4*)&base[row * C_ + col] = (uint4){0, 0, 0, 0};
    }
}

// ---------------- win_sum(s) over t, output transposed: sw_t[b][t][s] bf16 ------
__global__ __launch_bounds__(256) void winsum_kernel(const float* __restrict__ s,
                                                     ushort_t* __restrict__ sw_t) {
    int b = blockIdx.y;
    int t0 = blockIdx.x * 64;
    __shared__ float sb[128][101];
    int tid = threadIdx.x;
    for (int e = tid; e < 128 * 100; e += 256) {
        int sj = e / 100;
        int u = e - sj * 100;
        int gt = t0 - HALF + u;
        float v = 0.f;
        if (gt >= 0 && gt < T_) v = s[((size_t)(b * S_ + sj)) * T_ + gt];
        sb[sj][u] = v;
    }
    __syncthreads();
    for (int e = tid; e < 64 * 128; e += 256) {
        int tl = e >> 7;
        int sj = e & 127;
        float sum = 0.f;
#pragma unroll
        for (int d = 0; d < WLEN; ++d) sum += sb[sj][tl + d];
        sw_t[((size_t)(b * T_ + t0 + tl)) * S_ + sj] = f2bf(sum);
    }
}

// ---------------- fused adawin instance + leaky-relu ----------------------------
template <int INLAYOUT>
__global__ __launch_bounds__(256) void adawin_kernel(
    const void* __restrict__ xin_, const ushort_t* __restrict__ sw_t,
    const ushort_t* __restrict__ Wfc, const float* __restrict__ fcb,
    const float* __restrict__ alpha, const int* __restrict__ lengths,
    ushort_t* __restrict__ youtp) {
    int t0 = blockIdx.x * 64;
    int c0 = blockIdx.y * 64;
    int b = blockIdx.z;
    __shared__ __attribute__((aligned(16))) ushort_t smem[128 * 136 + 64 * 136];
    ushort_t (*As)[136] = (ushort_t(*)[136])smem;
    ushort_t (*Bs)[136] = (ushort_t(*)[136])(smem + 128 * 136);
    int tid = threadIdx.x;

    {
        int r = tid >> 4;
        int cseg = (tid & 15) * 8;
#pragma unroll
        for (int p = 0; p < 8; ++p) {
            int row = p * 16 + r;
            int grow = (row < 64) ? (c0 + row) : (448 + c0 + row);
            *(uint4*)&As[row][cseg] = *(const uint4*)&Wfc[(size_t)grow * 128 + cseg];
        }
    }
    {
        int tl = tid & 63;
        int sg = tid >> 6;
        const ushort_t* src = &sw_t[((size_t)(b * T_ + t0 + tl)) * S_];
#pragma unroll
        for (int j = 0; j < 4; ++j) {
            int col = sg * 32 + j * 8;
            *(uint4*)&Bs[tl][col] = *(const uint4*)&src[col];
        }
    }
    __syncthreads();

    int wave = tid >> 6, lane = tid & 63;
    int quad = lane >> 4, l = lane & 15;
    f32x4 accg[4], accb[4];
#pragma unroll
    for (int n = 0; n < 4; ++n) {
        accg[n] = (f32x4){0.f, 0.f, 0.f, 0.f};
        accb[n] = (f32x4){0.f, 0.f, 0.f, 0.f};
    }
    int rg = wave * 16 + l;
    int rb = 64 + wave * 16 + l;
#pragma unroll
    for (int ks = 0; ks < 4; ++ks) {
        int kc = ks * 32 + quad * 8;
        bf16x8 ag = *(const bf16x8*)&As[rg][kc];
        bf16x8 ab = *(const bf16x8*)&As[rb][kc];
#pragma unroll
        for (int n = 0; n < 4; ++n) {
            bf16x8 bb = *(const bf16x8*)&Bs[n * 16 + l][kc];
            accg[n] = MFMA16(ag, bb, accg[n]);
            accb[n] = MFMA16(ab, bb, accb[n]);
        }
    }

    __syncthreads();
    ushort_t (*Ts)[72] = (ushort_t(*)[72])smem;

    int len = lengths[b];
    float alph = alpha[0];
    const float* xf = (const float*)xin_;
    const ushort_t* xh = (const ushort_t*)xin_;
    int clocal = wave * 16 + quad * 4;
    int cbase = c0 + clocal;
#pragma unroll
    for (int n = 0; n < 4; ++n) {
        int t = t0 + n * 16 + l;
        int lo = t - HALF; if (lo < 0) lo = 0;
        int hi = t + HALF; if (hi > T_ - 1) hi = T_ - 1;
        float cnt = (float)(hi - lo + 1);
        int hv = hi < (len - 1) ? hi : (len - 1);
        int mdi = hv - lo + 1; if (mdi < 0) mdi = 0;
        float m = (t < len) ? 1.f : 0.f;
        float sc = m / ((float)mdi + 1e-9f);

        float xv[4];
        if (INLAYOUT == 0) {
#pragma unroll
            for (int j = 0; j < 4; ++j)
                xv[j] = xf[(size_t)(b * C_ + cbase + j) * T_ + t];
        } else {
            uint2 xraw = *(const uint2*)&xh[((size_t)(b * (T_ + 2) + 1 + t)) * C_ + cbase];
            xv[0] = bf2f((ushort_t)(xraw.x & 0xffff));
            xv[1] = bf2f((ushort_t)(xraw.x >> 16));
            xv[2] = bf2f((ushort_t)(xraw.y & 0xffff));
            xv[3] = bf2f((ushort_t)(xraw.y >> 16));
        }
        unsigned pk[2];
#pragma unroll
        for (int j = 0; j < 4; ++j) {
            int c = cbase + j;
            float gamma = (accg[n][j] + fcb[c] * cnt) * sc;
            float beta = (accb[n][j] + fcb[C_ + c] * cnt) * sc;
            float xn = fast_tanh(alph * xv[j]);
            float v = (1.f + gamma) * xn + beta;
            v = v > 0.f ? v : 0.2f * v;
            unsigned hv16 = (unsigned)f2bf(v);
            if (j & 1) pk[j >> 1] |= hv16 << 16;
            else pk[j >> 1] = hv16;
        }
        *(uint2*)&Ts[n * 16 + l][clocal] = (uint2){pk[0], pk[1]};
    }
    __syncthreads();
    {
        int row = tid >> 2;
        int seg = (tid & 3) * 16;
        size_t gbase = ((size_t)(b * (T_ + 2) + 1 + t0 + row)) * C_ + c0 + seg;
        *(uint4*)&youtp[gbase] = *(const uint4*)&Ts[row][seg];
        *(uint4*)&youtp[gbase + 8] = *(const uint4*)&Ts[row][seg + 8];
    }
}

// ---------------- conv1d k=3: 256x256-tile 8-wave phase-split MFMA GEMM ---------
// Block: 512 thr = 8 waves (2M x 4N), tile o=256 x t=256, 16 chunks of 32 in-ch
// x 3 taps (K-depth 96). Per chunk: 3 phases (one tap each): {12 ds_read_b128 ->
// issue glds batch -> s_barrier -> lgkmcnt(0) -> setprio(1) -> 16 MFMA32 ->
// setprio(0) -> s_barrier}. Staging per chunk = 80 glds (52 A + 22 B + 6 benign
// dummies) in wave-uniform batches b0=4/b1=3/b2=3 per wave, issued one full
// chunk ahead; boundary wait is COUNTED vmcnt(4) (b0 of chunk+2 stays in
// flight), drains to 0 only once at ch=14. LDS: A dbuf 2x52K + B dbuf 2x22K.
__device__ __forceinline__ void issue_g(int g, const char* img, const char* xt, int ch,
                                        char* Ab, char* Bb, int lane) {
    if (g < 52) {
        glds16(img + g * 1024 + lane * 16, Ab + g * 1024);
    } else if (g < 74) {
        int j = g - 52;
        int gi = j * 64 + lane;  // granule index in B tile (258 rows x 5 slots)
        int r = gi / 5;
        int gg = gi - r * 5;
        if (gg == 4) gg = 0;     // pad slot: clamp to valid source
        if (r > 257) r = 257;    // tail granules: benign duplicate of row 257
        glds16(xt + (size_t)r * 1024 + ch * 64 + gg * 16, Bb + j * 1024);
    } else {
        int j = g - 74;          // dummy: re-issue A granule j (same src+dst)
        glds16(img + j * 1024 + lane * 16, Ab + j * 1024);
    }
}
template <int G0, int G1>
__device__ __forceinline__ void issue_batch(const char* img, const char* xt, int ch,
                                            char* Ab, char* Bb, int wave, int lane) {
#pragma unroll
    for (int g = G0; g < G1; ++g) {
        if ((g & 7) != wave) continue;
        issue_g(g, img, xt, ch, Ab, Bb, lane);
    }
}

template <int EPI>
__global__ __launch_bounds__(512, 2) void conv_kernel(
    const ushort_t* __restrict__ Xp, const ushort_t* __restrict__ Wimg,
    const float* __restrict__ bias, const float* __restrict__ resid,
    ushort_t* __restrict__ out_bf, float* __restrict__ out_f) {
    int t0 = blockIdx.x * 256;
    int o0 = blockIdx.y * 256;
    int b = blockIdx.z;
    __shared__ __attribute__((aligned(16))) char smem[2 * A_BYTES + 2 * B_BYTES];  // 148 KB
    int tid = threadIdx.x;
    int lane = tid & 63, wave = tid >> 6;
    int l32 = lane & 31, khalf = lane >> 5;
    int wm = wave >> 2, wn = wave & 3;  // 2M x 4N wave grid

    const char* imgch = (const char*)Wimg + (size_t)blockIdx.y * 16 * IMGCH;
    const char* xt = (const char*)Xp + (size_t)(b * (T_ + 2) + t0) * 1024;  // row r <-> t0-1+r

    f32x16 acc[4][2];  // [m-frag][n-frag]
#pragma unroll
    for (int m = 0; m < 4; ++m)
#pragma unroll
        for (int nf = 0; nf < 2; ++nf)
#pragma unroll
            for (int r = 0; r < 16; ++r) acc[m][nf][r] = 0.f;

    char* A0 = smem;
    char* A1 = smem + A_BYTES;
    char* Bb0 = smem + 2 * A_BYTES;
    char* Bb1 = Bb0 + B_BYTES;

    // prologue: full stage(ch0) + b0(ch1); counted wait leaves ch1's 4 in flight
    issue_batch<0, 80>(imgch, xt, 0, A0, Bb0, wave, lane);
    issue_batch<0, 32>(imgch + IMGCH, xt, 1, A1, Bb1, wave, lane);
    asm volatile("s_waitcnt vmcnt(4)" ::: "memory");
    asm volatile("s_barrier" ::: "memory");

#pragma unroll 1
    for (int ch = 0; ch < 16; ++ch) {
        int cur = ch & 1;
        char* Ac = smem + cur * A_BYTES;
        char* Bc = smem + 2 * A_BYTES + cur * B_BYTES;
        char* An = smem + (cur ^ 1) * A_BYTES;
        char* Bn = smem + 2 * A_BYTES + (cur ^ 1) * B_BYTES;
        ushort_t (*As)[104] = (ushort_t(*)[104])Ac;
        ushort_t (*Bs)[40] = (ushort_t(*)[40])Bc;
        const char* img_n1 = imgch + (size_t)(ch + 1) * IMGCH;

#pragma unroll
        for (int p = 0; p < 3; ++p) {  // phase p == tap p; ksteps j = 2p, 2p+1
            bf16x8 af[2][4], bf[2][2];
#pragma unroll
            for (int m = 0; m < 4; ++m) {
                const ushort_t* ar = &As[wm * 128 + m * 32 + l32][p * 32 + khalf * 8];
                af[0][m] = *(const bf16x8*)ar;
                af[1][m] = *(const bf16x8*)(ar + 16);
            }
#pragma unroll
            for (int nf = 0; nf < 2; ++nf) {
                const ushort_t* br = &Bs[wn * 64 + nf * 32 + l32 + p][khalf * 8];
                bf[0][nf] = *(const bf16x8*)br;
                bf[1][nf] = *(const bf16x8*)(br + 16);
            }
            if (ch < 15) {
                if (p == 0) issue_batch<32, 56>(img_n1, xt, ch + 1, An, Bn, wave, lane);
                else if (p == 1) issue_batch<56, 80>(img_n1, xt, ch + 1, An, Bn, wave, lane);
            }
            asm volatile("s_barrier" ::: "memory");
            asm volatile("s_waitcnt lgkmcnt(0)" ::: "memory");
            __builtin_amdgcn_sched_barrier(0);
            __builtin_amdgcn_s_setprio(1);
#pragma unroll
            for (int ks = 0; ks < 2; ++ks)
#pragma unroll
                for (int m = 0; m < 4; ++m)
#pragma unroll
                    for (int nf = 0; nf < 2; ++nf)
                        acc[m][nf] = MFMA32(af[ks][m], bf[ks][nf], acc[m][nf]);
            __builtin_amdgcn_s_setprio(0);
            asm volatile("s_barrier" ::: "memory");
        }
        // chunk boundary: all waves done reading (Ac,Bc) -> safe to restage them
        if (ch < 14) {
            issue_batch<0, 32>(imgch + (size_t)(ch + 2) * IMGCH, xt, ch + 2, Ac, Bc,
                               wave, lane);
            asm volatile("s_waitcnt vmcnt(4)" ::: "memory");  // stage(ch+1) complete
            asm volatile("s_barrier" ::: "memory");
        } else if (ch == 14) {
            asm volatile("s_waitcnt vmcnt(0)" ::: "memory");
            asm volatile("s_barrier" ::: "memory");
        }
    }

    // epilogue: C/D layout col=lane&31 (t), row=(reg&3)+8*(reg>>2)+4*khalf (o)
    if (EPI == 0) {
        __syncthreads();
        ushort_t (*Ts)[264] = (ushort_t(*)[264])smem;  // 256*264*2 = 135168 B fits 148K
#pragma unroll
        for (int nf = 0; nf < 2; ++nf) {
            int trow = wn * 64 + nf * 32 + l32;
#pragma unroll
            for (int m = 0; m < 4; ++m) {
#pragma unroll
                for (int g = 0; g < 4; ++g) {
                    int oc = wm * 128 + m * 32 + g * 8 + khalf * 4;
                    unsigned pk[2];
#pragma unroll
                    for (int j = 0; j < 4; ++j) {
                        float v = acc[m][nf][g * 4 + j] + bias[o0 + oc + j];
                        unsigned hv16 = (unsigned)f2bf(v);
                        if (j & 1) pk[j >> 1] |= hv16 << 16;
                        else pk[j >> 1] = hv16;
                    }
                    *(uint2*)&Ts[trow][oc] = (uint2){pk[0], pk[1]};
                }
            }
        }
        __syncthreads();
        int row = tid >> 1;
        int colh = (tid & 1) * 128;
        size_t gbase = ((size_t)(b * (T_ + 2) + 1 + t0 + row)) * C_ + o0 + colh;
#pragma unroll
        for (int j = 0; j < 16; ++j)
            *(uint4*)&out_bf[gbase + j * 8] = *(const uint4*)&Ts[row][colh + j * 8];
    } else {
#pragma unroll
        for (int m = 0; m < 4; ++m)
#pragma unroll
            for (int nf = 0; nf < 2; ++nf) {
                int t = t0 + wn * 64 + nf * 32 + l32;
#pragma unroll
                for (int g = 0; g < 4; ++g) {
                    int oo = o0 + wm * 128 + m * 32 + g * 8 + khalf * 4;
#pragma unroll
                    for (int j = 0; j < 4; ++j) {
                        size_t off = (size_t)(b * C_ + oo + j) * T_ + t;
                        out_f[off] = (acc[m][nf][g * 4 + j] + bias[oo + j] + resid[off]) *
                                     0.70710678118654752f;
                    }
                }
            }
    }
}

extern "C" void kernel_launch(void* const* d_in, const int* in_sizes, int n_in,
                              void* d_out, int out_size, void* d_ws, size_t ws_size,
                              hipStream_t stream) {
    const float* x = (const float*)d_in[0];
    const float* s = (const float*)d_in[1];
    const int* lengths = (const int*)d_in[2];
    const float* fc1_w = (const float*)d_in[3];
    const float* fc1_b = (const float*)d_in[4];
    const float* alpha1 = (const float*)d_in[5];
    const float* conv1_w = (const float*)d_in[6];
    const float* conv1_b = (const float*)d_in[7];
    const float* fc2_w = (const float*)d_in[8];
    const float* fc2_b = (const float*)d_in[9];
    const float* alpha2 = (const float*)d_in[10];
    const float* conv2_w = (const float*)d_in[11];
    const float* conv2_b = (const float*)d_in[12];

    const size_t IMGB = (size_t)2 * 16 * IMGCH;  // 1703936 B per conv image
    char* ws = (char*)d_ws;
    ushort_t* sw_t = (ushort_t*)ws; ws += (size_t)B_ * T_ * S_ * 2;        // 8 MB
    ushort_t* Wfc = (ushort_t*)ws;  ws += (size_t)2 * 1024 * 128 * 2;      // 0.5 MB
    ushort_t* I1 = (ushort_t*)ws;   ws += IMGB;                            // 1.7 MB
    ushort_t* I2 = (ushort_t*)ws;   ws += IMGB;                            // 1.7 MB
    ushort_t* y2p = (ushort_t*)ws;  ws += (size_t)B_ * (T_ + 2) * C_ * 2;  // 33.6 MB
    ushort_t* y1p = (ushort_t*)ws;  ws += (size_t)B_ * (T_ + 2) * C_ * 2;  // 33.6 MB
    ws += 12 * 1024;  // glds over-read slack
    if ((size_t)(ws - (char*)d_ws) > ws_size) return;

    prep_weights<<<dim3(1024), dim3(256), 0, stream>>>(fc1_w, fc2_w, Wfc);
    prep_conv_images<<<dim3(832), dim3(256), 0, stream>>>(conv1_w, conv2_w, I1, I2);
    winsum_kernel<<<dim3(32, 16), dim3(256), 0, stream>>>(s, sw_t);
    zero_pads<<<dim3(16), dim3(256), 0, stream>>>(y1p, y2p);
    adawin_kernel<0><<<dim3(32, 8, 16), dim3(256), 0, stream>>>(
        (const void*)x, sw_t, Wfc, fc1_b, alpha1, lengths, y1p);
    conv_kernel<0><<<dim3(8, 2, 16), dim3(512), 0, stream>>>(
        y1p, I1, conv1_b, (const float*)nullptr, y2p, (float*)nullptr);
    adawin_kernel<1><<<dim3(32, 8, 16), dim3(256), 0, stream>>>(
        (const void*)y2p, sw_t, Wfc + 1024 * 128, fc2_b, alpha2, lengths, y1p);
    conv_kernel<1><<<dim3(8, 2, 16), dim3(512), 0, stream>>>(
        y1p, I2, conv2_b, x, (ushort_t*)nullptr, (float*)d_out);
}

// Round 5
// 347.058 us; speedup vs baseline: 1.0691x; 1.0691x over previous
//
#include <hip/hip_runtime.h>

#define B_ 16
#define C_ 512
#define S_ 128
#define T_ 2048
#define HALF 18
#define WLEN 37

typedef __bf16 bf16x8 __attribute__((ext_vector_type(8)));
typedef float f32x4 __attribute__((ext_vector_type(4)));
typedef float f32x16 __attribute__((ext_vector_type(16)));
typedef unsigned short ushort_t;

__device__ inline ushort_t f2bf(float x) {
    unsigned u = __float_as_uint(x);
    u += 0x7fffu + ((u >> 16) & 1u);  // RNE; inputs are finite
    return (ushort_t)(u >> 16);
}
__device__ inline float bf2f(ushort_t h) {
    return __uint_as_float(((unsigned)h) << 16);
}
__device__ inline float fast_tanh(float z) {
    float e = __expf(2.f * z);
    return 1.f - __fdividef(2.f, e + 1.f);
}
__device__ __forceinline__ void glds16(const void* g, void* l) {
    __builtin_amdgcn_global_load_lds(
        (const __attribute__((address_space(1))) unsigned*)g,
        (__attribute__((address_space(3))) unsigned*)l, 16, 0, 0);
}

#define MFMA16(a, b, c) __builtin_amdgcn_mfma_f32_16x16x32_bf16((a), (b), (c), 0, 0, 0)
#define MFMA32(a, b, c) __builtin_amdgcn_mfma_f32_32x32x16_bf16((a), (b), (c), 0, 0, 0)

// Conv image geometry: per conv [mb(2)][cc(32)] chunks of 28672 B.
// Each chunk IS the LDS A-tile [256 rows][112 B]: row = o-local, col byte
// c = tap*32 + khalf*16 + ch2*2 holds w[o=mb*256+row][i=cc*16+khalf*8+ch2][tap];
// bytes 96..111 of each row are zero pad (7 granules/row, odd -> conflict-free).
#define ACH_BYTES 28672  // 28 x 1024
#define BCH_BYTES 13312  // 13 x 1024 (258 rows x 48 B = 12384 used)
#define CH_BYTES (ACH_BYTES + BCH_BYTES)  // 41984

// ---------------- fused prep kernel: winsum + conv images + fc weights + pads --
__global__ __launch_bounds__(256) void prep_all(
    const float* __restrict__ s, ushort_t* __restrict__ sw_t,
    const float* __restrict__ fc1, const float* __restrict__ fc2,
    ushort_t* __restrict__ Wfc, const float* __restrict__ c1,
    const float* __restrict__ c2, ushort_t* __restrict__ I1,
    ushort_t* __restrict__ I2, ushort_t* __restrict__ y1p,
    ushort_t* __restrict__ y2p) {
    __shared__ float sb[128][101];
    int bid = blockIdx.x;
    int tid = threadIdx.x;
    if (bid < 512) {
        // ---- winsum(s) over t, output transposed: sw_t[b][t][s] bf16 ----
        int b = bid >> 5;
        int t0 = (bid & 31) * 64;
        for (int e = tid; e < 128 * 100; e += 256) {
            int sj = e / 100;
            int u = e - sj * 100;
            int gt = t0 - HALF + u;
            float v = 0.f;
            if (gt >= 0 && gt < T_) v = s[((size_t)(b * S_ + sj)) * T_ + gt];
            sb[sj][u] = v;
        }
        __syncthreads();
        for (int e = tid; e < 64 * 128; e += 256) {
            int tl = e >> 7;
            int sj = e & 127;
            float sum = 0.f;
#pragma unroll
            for (int d = 0; d < WLEN; ++d) sum += sb[sj][tl + d];
            sw_t[((size_t)(b * T_ + t0 + tl)) * S_ + sj] = f2bf(sum);
        }
    } else if (bid < 1408) {
        // ---- conv weight images (new 16-ch-chunk layout) ----
        int idx = (bid - 512) * 256 + tid;            // 16-B slot id
        const int per_conv = 2 * 32 * 1792;           // 114688 slots
        int conv = idx >= per_conv;
        int rr = conv ? idx - per_conv : idx;
        const float* src = conv ? c2 : c1;
        ushort_t* dst = conv ? I2 : I1;
        int chunk_id = rr / 1792;                     // 0..63
        int srem = rr - chunk_id * 1792;
        int mb = chunk_id >> 5, cc = chunk_id & 31;
        int off = srem * 16;
        int row = off / 112;
        int c = off - row * 112;                      // multiple of 16
        ushort_t vals[8];
        if (c >= 96) {
#pragma unroll
            for (int e = 0; e < 8; ++e) vals[e] = 0;
        } else {
            int tap = c >> 5;
            int ch_lo = (c & 31) >> 1;                // 0 or 8
            int o = mb * 256 + row;
            int ibase = cc * 16 + ch_lo;
#pragma unroll
            for (int e = 0; e < 8; ++e)
                vals[e] = f2bf(src[(size_t)(o * 512 + ibase + e) * 3 + tap]);
        }
        uint4 pk;
        pk.x = vals[0] | ((unsigned)vals[1] << 16);
        pk.y = vals[2] | ((unsigned)vals[3] << 16);
        pk.z = vals[4] | ((unsigned)vals[5] << 16);
        pk.w = vals[6] | ((unsigned)vals[7] << 16);
        *(uint4*)&dst[(size_t)rr * 8] = pk;
    } else if (bid < 2432) {
        // ---- fc weights fp32 -> bf16 ----
        const int n_fc = 1024 * 128;
        int idx = (bid - 1408) * 256 + tid;
        if (idx < n_fc) Wfc[idx] = f2bf(fc1[idx]);
        else if (idx < 2 * n_fc) Wfc[idx] = f2bf(fc2[idx - n_fc]);
    } else {
        // ---- zero halo rows (t=-1, t=T) of both padded buffers ----
        int t2 = (bid - 2432) * 256 + tid;
        if (t2 < 4096) {
            ushort_t* base = (t2 & 1) ? y2p : y1p;
            int r = t2 >> 1;
            int bb = r >> 7;
            int rowsel = (r >> 6) & 1;
            int col = (r & 63) * 8;
            size_t row = (size_t)bb * (T_ + 2) + (rowsel ? (T_ + 1) : 0);
            *(uint4*)&base[row * C_ + col] = (uint4){0, 0, 0, 0};
        }
    }
}

// ---------------- fused adawin instance + leaky-relu ----------------------------
template <int INLAYOUT>
__global__ __launch_bounds__(256) void adawin_kernel(
    const void* __restrict__ xin_, const ushort_t* __restrict__ sw_t,
    const ushort_t* __restrict__ Wfc, const float* __restrict__ fcb,
    const float* __restrict__ alpha, const int* __restrict__ lengths,
    ushort_t* __restrict__ youtp) {
    int t0 = blockIdx.x * 64;
    int c0 = blockIdx.y * 64;
    int b = blockIdx.z;
    __shared__ __attribute__((aligned(16))) ushort_t smem[128 * 136 + 64 * 136];
    ushort_t (*As)[136] = (ushort_t(*)[136])smem;
    ushort_t (*Bs)[136] = (ushort_t(*)[136])(smem + 128 * 136);
    int tid = threadIdx.x;

    {
        int r = tid >> 4;
        int cseg = (tid & 15) * 8;
#pragma unroll
        for (int p = 0; p < 8; ++p) {
            int row = p * 16 + r;
            int grow = (row < 64) ? (c0 + row) : (448 + c0 + row);
            *(uint4*)&As[row][cseg] = *(const uint4*)&Wfc[(size_t)grow * 128 + cseg];
        }
    }
    {
        int tl = tid & 63;
        int sg = tid >> 6;
        const ushort_t* src = &sw_t[((size_t)(b * T_ + t0 + tl)) * S_];
#pragma unroll
        for (int j = 0; j < 4; ++j) {
            int col = sg * 32 + j * 8;
            *(uint4*)&Bs[tl][col] = *(const uint4*)&src[col];
        }
    }
    __syncthreads();

    int wave = tid >> 6, lane = tid & 63;
    int quad = lane >> 4, l = lane & 15;
    f32x4 accg[4], accb[4];
#pragma unroll
    for (int n = 0; n < 4; ++n) {
        accg[n] = (f32x4){0.f, 0.f, 0.f, 0.f};
        accb[n] = (f32x4){0.f, 0.f, 0.f, 0.f};
    }
    int rg = wave * 16 + l;
    int rb = 64 + wave * 16 + l;
#pragma unroll
    for (int ks = 0; ks < 4; ++ks) {
        int kc = ks * 32 + quad * 8;
        bf16x8 ag = *(const bf16x8*)&As[rg][kc];
        bf16x8 ab = *(const bf16x8*)&As[rb][kc];
#pragma unroll
        for (int n = 0; n < 4; ++n) {
            bf16x8 bb = *(const bf16x8*)&Bs[n * 16 + l][kc];
            accg[n] = MFMA16(ag, bb, accg[n]);
            accb[n] = MFMA16(ab, bb, accb[n]);
        }
    }

    __syncthreads();
    ushort_t (*Ts)[72] = (ushort_t(*)[72])smem;

    int len = lengths[b];
    float alph = alpha[0];
    const float* xf = (const float*)xin_;
    const ushort_t* xh = (const ushort_t*)xin_;
    int clocal = wave * 16 + quad * 4;
    int cbase = c0 + clocal;
#pragma unroll
    for (int n = 0; n < 4; ++n) {
        int t = t0 + n * 16 + l;
        int lo = t - HALF; if (lo < 0) lo = 0;
        int hi = t + HALF; if (hi > T_ - 1) hi = T_ - 1;
        float cnt = (float)(hi - lo + 1);
        int hv = hi < (len - 1) ? hi : (len - 1);
        int mdi = hv - lo + 1; if (mdi < 0) mdi = 0;
        float m = (t < len) ? 1.f : 0.f;
        float sc = m / ((float)mdi + 1e-9f);

        float xv[4];
        if (INLAYOUT == 0) {
#pragma unroll
            for (int j = 0; j < 4; ++j)
                xv[j] = xf[(size_t)(b * C_ + cbase + j) * T_ + t];
        } else {
            uint2 xraw = *(const uint2*)&xh[((size_t)(b * (T_ + 2) + 1 + t)) * C_ + cbase];
            xv[0] = bf2f((ushort_t)(xraw.x & 0xffff));
            xv[1] = bf2f((ushort_t)(xraw.x >> 16));
            xv[2] = bf2f((ushort_t)(xraw.y & 0xffff));
            xv[3] = bf2f((ushort_t)(xraw.y >> 16));
        }
        unsigned pk[2];
#pragma unroll
        for (int j = 0; j < 4; ++j) {
            int c = cbase + j;
            float gamma = (accg[n][j] + fcb[c] * cnt) * sc;
            float beta = (accb[n][j] + fcb[C_ + c] * cnt) * sc;
            float xn = fast_tanh(alph * xv[j]);
            float v = (1.f + gamma) * xn + beta;
            v = v > 0.f ? v : 0.2f * v;
            unsigned hv16 = (unsigned)f2bf(v);
            if (j & 1) pk[j >> 1] |= hv16 << 16;
            else pk[j >> 1] = hv16;
        }
        *(uint2*)&Ts[n * 16 + l][clocal] = (uint2){pk[0], pk[1]};
    }
    __syncthreads();
    {
        int row = tid >> 2;
        int seg = (tid & 3) * 16;
        size_t gbase = ((size_t)(b * (T_ + 2) + 1 + t0 + row)) * C_ + c0 + seg;
        *(uint4*)&youtp[gbase] = *(const uint4*)&Ts[row][seg];
        *(uint4*)&youtp[gbase + 8] = *(const uint4*)&Ts[row][seg + 8];
    }
}

// ---------------- conv1d k=3: 256x256 tile, 32 small K-chunks, depth-2 pipeline -
// Block: 512 thr = 8 waves (2M x 4N). Chunk = 16 in-ch x 3 taps. LDS: 3 buffers
// of (A 28K + B 13K). Stage(c+2) issued at top of chunk c (6 glds/wave,
// wave-uniform via dummy A re-issues) -> 12 glds/wave (~96 KB/CU) in flight at
// all times. Per chunk: 18 ds_read_b128 + 24 MFMA32 per wave, compiler-scheduled
// (fine-grained lgkmcnt, reads overlap MFMAs). Boundary: vmcnt(6) completes
// stage(c+1), leaves stage(c+2) in flight; ONE barrier per chunk.
__device__ __forceinline__ void stage_chunk(const char* img, const char* xt, int cc,
                                            char* buf, int wave, int lane) {
    char* Ab = buf;
    char* Bb = buf + ACH_BYTES;
#pragma unroll
    for (int k = 0; k < 6; ++k) {
        int g = wave + 8 * k;  // 0..47
        if (g < 28) {
            glds16(img + g * 1024 + lane * 16, Ab + g * 1024);
        } else if (g < 41) {
            int j = g - 28;  // B granule 0..12
            int off = j * 1024 + lane * 16;
            int r = off / 48;
            int sl = (off - r * 48) >> 4;
            if (sl == 2) sl = 0;   // pad slot: benign duplicate
            if (r > 257) r = 257;  // tail: clamp to last valid row
            glds16(xt + (size_t)r * 1024 + cc * 32 + sl * 16, Bb + j * 1024);
        } else {
            int j = g - 41;  // dummy: re-issue A granule j (same src+dst)
            glds16(img + j * 1024 + lane * 16, Ab + j * 1024);
        }
    }
}

template <int EPI>
__global__ __launch_bounds__(512, 2) void conv_kernel(
    const ushort_t* __restrict__ Xp, const ushort_t* __restrict__ Wimg,
    const float* __restrict__ bias, const float* __restrict__ resid,
    ushort_t* __restrict__ out_bf, float* __restrict__ out_f) {
    int t0 = blockIdx.x * 256;
    int o0 = blockIdx.y * 256;
    int b = blockIdx.z;
    __shared__ __attribute__((aligned(16))) char smem[135168];  // 3*41984; Ts fits
    int tid = threadIdx.x;
    int lane = tid & 63, wave = tid >> 6;
    int l32 = lane & 31, khalf = lane >> 5;
    int wm = wave >> 2, wn = wave & 3;  // 2M x 4N wave grid

    const char* imgcc = (const char*)Wimg + (size_t)blockIdx.y * 32 * ACH_BYTES;
    const char* xt = (const char*)Xp + (size_t)(b * (T_ + 2) + t0) * 1024;  // row r <-> t0-1+r

    f32x16 acc[4][2];  // [m-frag][n-frag]
#pragma unroll
    for (int m = 0; m < 4; ++m)
#pragma unroll
        for (int nf = 0; nf < 2; ++nf)
#pragma unroll
            for (int r = 0; r < 16; ++r) acc[m][nf][r] = 0.f;

    // prologue: stage chunks 0 and 1; wait for chunk 0 (leave 1 in flight)
    stage_chunk(imgcc, xt, 0, smem, wave, lane);
    stage_chunk(imgcc + ACH_BYTES, xt, 1, smem + CH_BYTES, wave, lane);
    asm volatile("s_waitcnt vmcnt(6)" ::: "memory");
    asm volatile("s_barrier" ::: "memory");

    int cur = 0;
#pragma unroll 1
    for (int c = 0; c < 32; ++c) {
        char* buf = smem + cur * CH_BYTES;
        if (c + 2 < 32) {
            int s2 = cur + 2; if (s2 >= 3) s2 -= 3;
            stage_chunk(imgcc + (size_t)(c + 2) * ACH_BYTES, xt, c + 2,
                        smem + s2 * CH_BYTES, wave, lane);
        }
        ushort_t (*As)[56] = (ushort_t(*)[56])buf;
        ushort_t (*Bs)[24] = (ushort_t(*)[24])(buf + ACH_BYTES);
#pragma unroll
        for (int p = 0; p < 3; ++p) {
            bf16x8 a[4], bv[2];
#pragma unroll
            for (int m = 0; m < 4; ++m)
                a[m] = *(const bf16x8*)&As[wm * 128 + m * 32 + l32][p * 16 + khalf * 8];
#pragma unroll
            for (int nf = 0; nf < 2; ++nf)
                bv[nf] = *(const bf16x8*)&Bs[wn * 64 + nf * 32 + l32 + p][khalf * 8];
#pragma unroll
            for (int m = 0; m < 4; ++m)
#pragma unroll
                for (int nf = 0; nf < 2; ++nf)
                    acc[m][nf] = MFMA32(a[m], bv[nf], acc[m][nf]);
        }
        // boundary: complete stage(c+1); keep stage(c+2)'s 6 loads in flight
        if (c + 2 < 32) asm volatile("s_waitcnt vmcnt(6)" ::: "memory");
        else if (c + 1 < 32) asm volatile("s_waitcnt vmcnt(0)" ::: "memory");
        asm volatile("s_barrier" ::: "memory");
        cur = cur + 1; if (cur >= 3) cur = 0;
    }

    // epilogue: C/D layout col=lane&31 (t), row=(reg&3)+8*(reg>>2)+4*khalf (o)
    if (EPI == 0) {
        __syncthreads();
        ushort_t (*Ts)[264] = (ushort_t(*)[264])smem;  // 256*264*2 = 135168 B
#pragma unroll
        for (int nf = 0; nf < 2; ++nf) {
            int trow = wn * 64 + nf * 32 + l32;
#pragma unroll
            for (int m = 0; m < 4; ++m) {
#pragma unroll
                for (int g = 0; g < 4; ++g) {
                    int oc = wm * 128 + m * 32 + g * 8 + khalf * 4;
                    unsigned pk[2];
#pragma unroll
                    for (int j = 0; j < 4; ++j) {
                        float v = acc[m][nf][g * 4 + j] + bias[o0 + oc + j];
                        unsigned hv16 = (unsigned)f2bf(v);
                        if (j & 1) pk[j >> 1] |= hv16 << 16;
                        else pk[j >> 1] = hv16;
                    }
                    *(uint2*)&Ts[trow][oc] = (uint2){pk[0], pk[1]};
                }
            }
        }
        __syncthreads();
        int row = tid >> 1;
        int colh = (tid & 1) * 128;
        size_t gbase = ((size_t)(b * (T_ + 2) + 1 + t0 + row)) * C_ + o0 + colh;
#pragma unroll
        for (int j = 0; j < 16; ++j)
            *(uint4*)&out_bf[gbase + j * 8] = *(const uint4*)&Ts[row][colh + j * 8];
    } else {
#pragma unroll
        for (int m = 0; m < 4; ++m)
#pragma unroll
            for (int nf = 0; nf < 2; ++nf) {
                int t = t0 + wn * 64 + nf * 32 + l32;
#pragma unroll
                for (int g = 0; g < 4; ++g) {
                    int oo = o0 + wm * 128 + m * 32 + g * 8 + khalf * 4;
#pragma unroll
                    for (int j = 0; j < 4; ++j) {
                        size_t off = (size_t)(b * C_ + oo + j) * T_ + t;
                        out_f[off] = (acc[m][nf][g * 4 + j] + bias[oo + j] + resid[off]) *
                                     0.70710678118654752f;
                    }
                }
            }
    }
}

extern "C" void kernel_launch(void* const* d_in, const int* in_sizes, int n_in,
                              void* d_out, int out_size, void* d_ws, size_t ws_size,
                              hipStream_t stream) {
    const float* x = (const float*)d_in[0];
    const float* s = (const float*)d_in[1];
    const int* lengths = (const int*)d_in[2];
    const float* fc1_w = (const float*)d_in[3];
    const float* fc1_b = (const float*)d_in[4];
    const float* alpha1 = (const float*)d_in[5];
    const float* conv1_w = (const float*)d_in[6];
    const float* conv1_b = (const float*)d_in[7];
    const float* fc2_w = (const float*)d_in[8];
    const float* fc2_b = (const float*)d_in[9];
    const float* alpha2 = (const float*)d_in[10];
    const float* conv2_w = (const float*)d_in[11];
    const float* conv2_b = (const float*)d_in[12];

    const size_t IMGB = (size_t)2 * 32 * ACH_BYTES;  // 1835008 B per conv image
    char* ws = (char*)d_ws;
    ushort_t* sw_t = (ushort_t*)ws; ws += (size_t)B_ * T_ * S_ * 2;        // 8 MB
    ushort_t* Wfc = (ushort_t*)ws;  ws += (size_t)2 * 1024 * 128 * 2;      // 0.5 MB
    ushort_t* I1 = (ushort_t*)ws;   ws += IMGB;                            // 1.84 MB
    ushort_t* I2 = (ushort_t*)ws;   ws += IMGB;                            // 1.84 MB
    ushort_t* y2p = (ushort_t*)ws;  ws += (size_t)B_ * (T_ + 2) * C_ * 2;  // 33.6 MB
    ushort_t* y1p = (ushort_t*)ws;  ws += (size_t)B_ * (T_ + 2) * C_ * 2;  // 33.6 MB
    ws += 12 * 1024;  // slack
    if ((size_t)(ws - (char*)d_ws) > ws_size) return;

    prep_all<<<dim3(2448), dim3(256), 0, stream>>>(
        s, sw_t, fc1_w, fc2_w, Wfc, conv1_w, conv2_w, I1, I2, y1p, y2p);
    adawin_kernel<0><<<dim3(32, 8, 16), dim3(256), 0, stream>>>(
        (const void*)x, sw_t, Wfc, fc1_b, alpha1, lengths, y1p);
    conv_kernel<0><<<dim3(8, 2, 16), dim3(512), 0, stream>>>(
        y1p, I1, conv1_b, (const float*)nullptr, y2p, (float*)nullptr);
    adawin_kernel<1><<<dim3(32, 8, 16), dim3(256), 0, stream>>>(
        (const void*)y2p, sw_t, Wfc + 1024 * 128, fc2_b, alpha2, lengths, y1p);
    conv_kernel<1><<<dim3(8, 2, 16), dim3(512), 0, stream>>>(
        y1p, I2, conv2_b, x, (ushort_t*)nullptr, (float*)d_out);
}